// Round 1
// baseline (545.255 us; speedup 1.0000x reference)
//
#include <hip/hip_runtime.h>
#include <math.h>

// Problem constants
#define VOCAB 400000
#define D     50
#define DP    52      // padded row (13 float4), cols 50,51 zero
#define NQ    13      // DP / 4
#define MM    128     // M
#define LL    512     // L
#define BB    64      // B
#define CHUNK 64      // tokens per block
#define TPR   8       // tokens per staging round
#define ROUNDS (CHUNK / TPR)
#define NTHREADS 256

__global__ void __launch_bounds__(1024) zero_kernel(float* __restrict__ out) {
    out[blockIdx.x * 1024 + threadIdx.x] = 0.0f;
}

__global__ void __launch_bounds__(NTHREADS, 2)
qdnn_main(const int*   __restrict__ x,
          const float* __restrict__ amp_table,
          const float* __restrict__ pha_table,
          const float* __restrict__ mix_table,
          const float* __restrict__ kernel_real,
          const float* __restrict__ kernel_imag,
          float* __restrict__ out)
{
    __shared__ float4 s_knr4[MM * NQ];        // 26624 B
    __shared__ float4 s_kni4[MM * NQ];        // 26624 B
    __shared__ float4 s_vr4[2][TPR * NQ];     //  3328 B
    __shared__ float4 s_vi4[2][TPR * NQ];     //  3328 B
    __shared__ int    s_x[LL];                //  2048 B
    __shared__ float  s_w[LL];                //  2048 B
    __shared__ float  s_red[8];               // total ~64.0 KB -> 2 blocks/CU

    const int tid   = threadIdx.x;
    const int b     = blockIdx.x >> 3;
    const int chunk = blockIdx.x & 7;
    const int m     = tid & (MM - 1);
    const int half  = tid >> 7;               // 0: tokens 0-3 of round, 1: tokens 4-7

    // ---- phase 0: load token row + stage kernel tables into LDS (zero-padded)
    const int* xg = x + b * LL;
    s_x[tid]       = xg[tid];
    s_x[tid + 256] = xg[tid + 256];

    float* knr = (float*)s_knr4;
    float* kni = (float*)s_kni4;
    for (int j = tid; j < MM * DP; j += NTHREADS) {
        int row = j / DP;
        int d   = j - row * DP;
        float vr = 0.0f, vi = 0.0f;
        if (d < D) {
            vr = kernel_real[row * D + d];
            vi = kernel_imag[row * D + d];
        }
        knr[j] = vr;
        kni[j] = vi;
    }
    __syncthreads();

    // ---- phase 1: softmax over mix logits (full L=512 of this b, redundant per chunk)
    float v0 = mix_table[s_x[tid]];
    float v1 = mix_table[s_x[tid + 256]];
    float lmax = fmaxf(v0, v1);
    #pragma unroll
    for (int off = 32; off > 0; off >>= 1)
        lmax = fmaxf(lmax, __shfl_down(lmax, off));
    const int wv = tid >> 6, lane = tid & 63;
    if (lane == 0) s_red[wv] = lmax;
    __syncthreads();
    const float bmax = fmaxf(fmaxf(s_red[0], s_red[1]), fmaxf(s_red[2], s_red[3]));
    const float e0 = __expf(v0 - bmax);
    const float e1 = __expf(v1 - bmax);
    s_w[tid]       = e0;
    s_w[tid + 256] = e1;
    float esum = e0 + e1;
    #pragma unroll
    for (int off = 32; off > 0; off >>= 1)
        esum += __shfl_down(esum, off);
    if (lane == 0) s_red[4 + wv] = esum;
    __syncthreads();
    const float inv = 1.0f / (s_red[4] + s_red[5] + s_red[6] + s_red[7]);
    s_w[tid]       *= inv;
    s_w[tid + 256] *= inv;

    // ---- phase 2: per-m inverse squared norm (replaces explicit normalization)
    float s2 = 0.0f;
    for (int d = 0; d < D; ++d) {
        float a = knr[m * DP + d], c = kni[m * DP + d];
        s2 = fmaf(a, a, fmaf(c, c, s2));
    }
    s2 = 1.0f / s2;

    // kernel row -> registers (26 float4)
    float4 krg[NQ], kig[NQ];
    {
        const float4* krow  = s_knr4 + m * NQ;
        const float4* kirow = s_kni4 + m * NQ;
        #pragma unroll
        for (int q = 0; q < NQ; ++q) { krg[q] = krow[q]; kig[q] = kirow[q]; }
    }

    // per-thread staging item decomposition (416 items = 8 tok x 52 cols)
    const int  j0 = tid, j1 = tid + 256;
    const int  tok0 = j0 / DP, d0 = j0 - tok0 * DP;
    const int  tok1 = j1 / DP, d1 = j1 - tok1 * DP;
    const bool p0v = (d0 < D);
    const bool has1 = (j1 < TPR * DP);
    const bool p1v = has1 && (d1 < D);
    const int  lbase = chunk * CHUNK;

    // ---- prologue: stage round 0 into buffer 0
    {
        float a0 = 0.f, q0 = 0.f, a1 = 0.f, q1 = 0.f;
        if (p0v) { int idx = s_x[lbase + tok0]; a0 = amp_table[idx * D + d0]; q0 = pha_table[idx * D + d0]; }
        if (p1v) { int idx = s_x[lbase + tok1]; a1 = amp_table[idx * D + d1]; q1 = pha_table[idx * D + d1]; }
        float* vr = (float*)s_vr4[0];
        float* vi = (float*)s_vi4[0];
        float sn, cs;
        __sincosf(q0, &sn, &cs);
        vr[j0] = p0v ? a0 * cs : 0.0f;
        vi[j0] = p0v ? a0 * sn : 0.0f;
        if (has1) {
            __sincosf(q1, &sn, &cs);
            vr[j1] = p1v ? a1 * cs : 0.0f;
            vi[j1] = p1v ? a1 * sn : 0.0f;
        }
    }
    __syncthreads();

    // ---- main loop: double-buffered, next-round gathers issued before FMAs
    float pacc = 0.0f;
    for (int r = 0; r < ROUNDS; ++r) {
        const int cur = r & 1;

        float a0 = 0.f, q0 = 0.f, a1 = 0.f, q1 = 0.f;
        if (r < ROUNDS - 1) {
            const int lb = lbase + (r + 1) * TPR;
            if (p0v) { int idx = s_x[lb + tok0]; a0 = amp_table[idx * D + d0]; q0 = pha_table[idx * D + d0]; }
            if (p1v) { int idx = s_x[lb + tok1]; a1 = amp_table[idx * D + d1]; q1 = pha_table[idx * D + d1]; }
        }

        const float* wrow = s_w + lbase + r * TPR;
        #pragma unroll
        for (int t = 0; t < 4; ++t) {
            const int tok = half * 4 + t;
            const float4* vr4 = s_vr4[cur] + tok * NQ;
            const float4* vi4 = s_vi4[cur] + tok * NQ;
            float Ar0 = 0.f, Ar1 = 0.f, Ai0 = 0.f, Ai1 = 0.f;
            #pragma unroll
            for (int q = 0; q < NQ; ++q) {
                const float4 rv = vr4[q], iv = vi4[q];
                const float4 kr = krg[q], ki = kig[q];
                Ar0 = fmaf(kr.x, rv.x, Ar0); Ar0 = fmaf(ki.x, iv.x, Ar0);
                Ai0 = fmaf(kr.x, iv.x, Ai0); Ai0 = fmaf(-ki.x, rv.x, Ai0);
                Ar1 = fmaf(kr.y, rv.y, Ar1); Ar1 = fmaf(ki.y, iv.y, Ar1);
                Ai1 = fmaf(kr.y, iv.y, Ai1); Ai1 = fmaf(-ki.y, rv.y, Ai1);
                Ar0 = fmaf(kr.z, rv.z, Ar0); Ar0 = fmaf(ki.z, iv.z, Ar0);
                Ai0 = fmaf(kr.z, iv.z, Ai0); Ai0 = fmaf(-ki.z, rv.z, Ai0);
                Ar1 = fmaf(kr.w, rv.w, Ar1); Ar1 = fmaf(ki.w, iv.w, Ar1);
                Ai1 = fmaf(kr.w, iv.w, Ai1); Ai1 = fmaf(-ki.w, rv.w, Ai1);
            }
            const float Ar = Ar0 + Ar1, Ai = Ai0 + Ai1;
            pacc = fmaf(wrow[tok], fmaf(Ar, Ar, Ai * Ai), pacc);
        }

        if (r < ROUNDS - 1) {
            const int nxt = cur ^ 1;
            float* vr = (float*)s_vr4[nxt];
            float* vi = (float*)s_vi4[nxt];
            float sn, cs;
            __sincosf(q0, &sn, &cs);
            vr[j0] = p0v ? a0 * cs : 0.0f;
            vi[j0] = p0v ? a0 * sn : 0.0f;
            if (has1) {
                __sincosf(q1, &sn, &cs);
                vr[j1] = p1v ? a1 * cs : 0.0f;
                vi[j1] = p1v ? a1 * sn : 0.0f;
            }
        }
        __syncthreads();
    }

    // ---- epilogue: combine the two token-halves, scale by 1/||row||^2, accumulate
    float* pbuf = (float*)s_vr4;   // safe to reuse after final barrier
    pbuf[tid] = pacc;
    __syncthreads();
    if (tid < MM) {
        const float p = (pbuf[tid] + pbuf[tid + MM]) * s2;
        atomicAdd(&out[b * MM + tid], p);
    }
}

extern "C" void kernel_launch(void* const* d_in, const int* in_sizes, int n_in,
                              void* d_out, int out_size, void* d_ws, size_t ws_size,
                              hipStream_t stream) {
    const int*   xx  = (const int*)d_in[0];
    const float* amp = (const float*)d_in[1];
    const float* pha = (const float*)d_in[2];
    const float* mix = (const float*)d_in[3];
    const float* kr  = (const float*)d_in[4];
    const float* ki  = (const float*)d_in[5];
    float* out = (float*)d_out;

    // zero-init output (harness poisons d_out with 0xAA before every launch)
    hipLaunchKernelGGL(zero_kernel, dim3((BB * MM) / 1024), dim3(1024), 0, stream, out);
    // main fused kernel: 512 blocks = 64 b x 8 chunks, 2 blocks/CU
    hipLaunchKernelGGL(qdnn_main, dim3(BB * 8), dim3(NTHREADS), 0, stream,
                       xx, amp, pha, mix, kr, ki, out);
}

// Round 2
// 181.802 us; speedup vs baseline: 2.9992x; 2.9992x over previous
//
#include <hip/hip_runtime.h>
#include <math.h>

// Problem constants
#define VOCAB 400000
#define D     50
#define DP    56        // padded token row (14 float4), cols 50..55 zero
#define ROWQ  14        // float4 per padded token row
#define NQH   7         // float4 quads per d-half (28 floats)
#define MM    128       // M
#define LL    512       // L
#define BB    64        // B
#define NCHUNK 16       // chunks per sequence
#define CHUNK 32        // tokens per block
#define TPR   8         // tokens per staging round
#define ROUNDS (CHUNK / TPR)
#define ITEMS (TPR * DP)   // 448 staging items per round
#define NTHREADS 256

__global__ void __launch_bounds__(1024) zero_kernel(float* __restrict__ out) {
    out[blockIdx.x * 1024 + threadIdx.x] = 0.0f;
}

// 256 threads = 128 m-rows x 2 d-halves; half-partner is lane^32 (same wave)
// so partial complex dot products combine with one __shfl_xor per token.
// Per-thread kernel fragment = 14 float4 = 56 VGPRs -> no spill (R1 lesson:
// 104-VGPR fragment cache spilled to scratch -> 1.8 GB HBM traffic).
__global__ void __launch_bounds__(NTHREADS)
qdnn_main(const int*   __restrict__ x,
          const float* __restrict__ amp_table,
          const float* __restrict__ pha_table,
          const float* __restrict__ mix_table,
          const float* __restrict__ kernel_real,
          const float* __restrict__ kernel_imag,
          float* __restrict__ out)
{
    __shared__ int    s_x[LL];                 // 2048 B
    __shared__ float  s_w[LL];                 // 2048 B
    __shared__ float  s_red[8];
    __shared__ float4 s_vr4[2][TPR * ROWQ];    // 3584 B
    __shared__ float4 s_vi4[2][TPR * ROWQ];    // 3584 B   total ~11.3 KB

    const int tid   = threadIdx.x;
    const int b     = blockIdx.x >> 4;
    const int chunk = blockIdx.x & (NCHUNK - 1);
    const int wave  = tid >> 6;
    const int lane  = tid & 63;
    const int half  = lane >> 5;               // d-half: 0 -> d 0..27, 1 -> d 28..55
    const int m     = wave * 32 + (lane & 31); // 0..127

    // ---- phase 0: sequence token ids into LDS
    const int* xg = x + b * LL;
    s_x[tid]       = xg[tid];
    s_x[tid + 256] = xg[tid + 256];
    __syncthreads();

    // ---- phase 1: softmax over mix logits (full L=512, redundant per chunk)
    float v0 = mix_table[s_x[tid]];
    float v1 = mix_table[s_x[tid + 256]];
    float lmax = fmaxf(v0, v1);
    #pragma unroll
    for (int off = 32; off > 0; off >>= 1)
        lmax = fmaxf(lmax, __shfl_down(lmax, off));
    if (lane == 0) s_red[wave] = lmax;
    __syncthreads();
    const float bmax = fmaxf(fmaxf(s_red[0], s_red[1]), fmaxf(s_red[2], s_red[3]));
    const float e0 = __expf(v0 - bmax);
    const float e1 = __expf(v1 - bmax);
    s_w[tid]       = e0;
    s_w[tid + 256] = e1;
    float esum = e0 + e1;
    #pragma unroll
    for (int off = 32; off > 0; off >>= 1)
        esum += __shfl_down(esum, off);
    if (lane == 0) s_red[4 + wave] = esum;
    __syncthreads();
    const float inv = 1.0f / (s_red[4] + s_red[5] + s_red[6] + s_red[7]);
    s_w[tid]       *= inv;
    s_w[tid + 256] *= inv;
    // (prologue's __syncthreads below orders these writes before loop reads)

    // ---- phase 2: kernel fragment -> registers (half row: 7 float4 x 2 tables)
    // Tables are 51 KB total -> L2-resident across all 1024 blocks.
    float4 krg[NQH], kig[NQH];
    #pragma unroll
    for (int q = 0; q < NQH; ++q) {
        const int dbase = half * 28 + q * 4;
        float4 a, c;
        a.x = (dbase + 0 < D) ? kernel_real[m * D + dbase + 0] : 0.0f;
        a.y = (dbase + 1 < D) ? kernel_real[m * D + dbase + 1] : 0.0f;
        a.z = (dbase + 2 < D) ? kernel_real[m * D + dbase + 2] : 0.0f;
        a.w = (dbase + 3 < D) ? kernel_real[m * D + dbase + 3] : 0.0f;
        c.x = (dbase + 0 < D) ? kernel_imag[m * D + dbase + 0] : 0.0f;
        c.y = (dbase + 1 < D) ? kernel_imag[m * D + dbase + 1] : 0.0f;
        c.z = (dbase + 2 < D) ? kernel_imag[m * D + dbase + 2] : 0.0f;
        c.w = (dbase + 3 < D) ? kernel_imag[m * D + dbase + 3] : 0.0f;
        krg[q] = a; kig[q] = c;
    }

    // inverse squared row norm (replaces explicit normalization; no sqrt)
    float s2p = 0.0f;
    #pragma unroll
    for (int q = 0; q < NQH; ++q) {
        const float4 a = krg[q], c = kig[q];
        s2p = fmaf(a.x, a.x, fmaf(c.x, c.x, s2p));
        s2p = fmaf(a.y, a.y, fmaf(c.y, c.y, s2p));
        s2p = fmaf(a.z, a.z, fmaf(c.z, c.z, s2p));
        s2p = fmaf(a.w, a.w, fmaf(c.w, c.w, s2p));
    }
    s2p += __shfl_xor(s2p, 32);
    const float s2 = 1.0f / s2p;

    // ---- staging decomposition: 448 items = 8 tokens x 56 padded cols
    const int  j0 = tid,        tok0 = j0 / DP, d0 = j0 - tok0 * DP;
    const int  j1 = tid + 256,  tok1 = j1 / DP, d1 = j1 - tok1 * DP;
    const bool p0v  = (d0 < D);
    const bool has1 = (j1 < ITEMS);
    const bool p1v  = has1 && (d1 < D);
    const int  lbase = chunk * CHUNK;

    // ---- prologue: stage round 0 into buffer 0
    {
        float a0 = 0.f, q0 = 0.f, a1 = 0.f, q1 = 0.f;
        if (p0v) { int idx = s_x[lbase + tok0]; a0 = amp_table[idx * D + d0]; q0 = pha_table[idx * D + d0]; }
        if (p1v) { int idx = s_x[lbase + tok1]; a1 = amp_table[idx * D + d1]; q1 = pha_table[idx * D + d1]; }
        float* vr = (float*)s_vr4[0];
        float* vi = (float*)s_vi4[0];
        float sn, cs;
        __sincosf(q0, &sn, &cs);
        vr[j0] = p0v ? a0 * cs : 0.0f;
        vi[j0] = p0v ? a0 * sn : 0.0f;
        if (has1) {
            __sincosf(q1, &sn, &cs);
            vr[j1] = p1v ? a1 * cs : 0.0f;
            vi[j1] = p1v ? a1 * sn : 0.0f;
        }
    }
    __syncthreads();

    // ---- main loop: double-buffered, next-round gathers issued before FMAs
    float pacc = 0.0f;
    for (int r = 0; r < ROUNDS; ++r) {
        const int cur = r & 1;

        float a0 = 0.f, q0 = 0.f, a1 = 0.f, q1 = 0.f;
        if (r < ROUNDS - 1) {
            const int lb = lbase + (r + 1) * TPR;
            if (p0v) { int idx = s_x[lb + tok0]; a0 = amp_table[idx * D + d0]; q0 = pha_table[idx * D + d0]; }
            if (p1v) { int idx = s_x[lb + tok1]; a1 = amp_table[idx * D + d1]; q1 = pha_table[idx * D + d1]; }
        }

        const float* wrow = s_w + lbase + r * TPR;
        #pragma unroll
        for (int t = 0; t < TPR; ++t) {
            const float4* vr4 = s_vr4[cur] + t * ROWQ + half * NQH;
            const float4* vi4 = s_vi4[cur] + t * ROWQ + half * NQH;
            float Ar0 = 0.f, Ar1 = 0.f, Ai0 = 0.f, Ai1 = 0.f;
            #pragma unroll
            for (int q = 0; q < NQH; ++q) {
                const float4 rv = vr4[q], iv = vi4[q];
                const float4 kr = krg[q], ki = kig[q];
                Ar0 = fmaf(kr.x, rv.x, Ar0); Ar0 = fmaf(ki.x, iv.x, Ar0);
                Ai0 = fmaf(kr.x, iv.x, Ai0); Ai0 = fmaf(-ki.x, rv.x, Ai0);
                Ar1 = fmaf(kr.y, rv.y, Ar1); Ar1 = fmaf(ki.y, iv.y, Ar1);
                Ai1 = fmaf(kr.y, iv.y, Ai1); Ai1 = fmaf(-ki.y, rv.y, Ai1);
                Ar0 = fmaf(kr.z, rv.z, Ar0); Ar0 = fmaf(ki.z, iv.z, Ar0);
                Ai0 = fmaf(kr.z, iv.z, Ai0); Ai0 = fmaf(-ki.z, rv.z, Ai0);
                Ar1 = fmaf(kr.w, rv.w, Ar1); Ar1 = fmaf(ki.w, iv.w, Ar1);
                Ai1 = fmaf(kr.w, iv.w, Ai1); Ai1 = fmaf(-ki.w, rv.w, Ai1);
            }
            float Ar = Ar0 + Ar1, Ai = Ai0 + Ai1;
            // combine the two d-halves (partner lane = lane^32, same wave)
            Ar += __shfl_xor(Ar, 32);
            Ai += __shfl_xor(Ai, 32);
            pacc = fmaf(wrow[t], fmaf(Ar, Ar, Ai * Ai), pacc);
        }

        if (r < ROUNDS - 1) {
            const int nxt = cur ^ 1;
            float* vr = (float*)s_vr4[nxt];
            float* vi = (float*)s_vi4[nxt];
            float sn, cs;
            __sincosf(q0, &sn, &cs);
            vr[j0] = p0v ? a0 * cs : 0.0f;
            vi[j0] = p0v ? a0 * sn : 0.0f;
            if (has1) {
                __sincosf(q1, &sn, &cs);
                vr[j1] = p1v ? a1 * cs : 0.0f;
                vi[j1] = p1v ? a1 * sn : 0.0f;
            }
        }
        __syncthreads();
    }

    // ---- epilogue: both halves hold identical pacc after shuffles; half 0 writes
    if (half == 0) {
        atomicAdd(&out[b * MM + m], pacc * s2);
    }
}

extern "C" void kernel_launch(void* const* d_in, const int* in_sizes, int n_in,
                              void* d_out, int out_size, void* d_ws, size_t ws_size,
                              hipStream_t stream) {
    const int*   xx  = (const int*)d_in[0];
    const float* amp = (const float*)d_in[1];
    const float* pha = (const float*)d_in[2];
    const float* mix = (const float*)d_in[3];
    const float* kr  = (const float*)d_in[4];
    const float* ki  = (const float*)d_in[5];
    float* out = (float*)d_out;

    // zero-init output (harness poisons d_out with 0xAA before every launch)
    hipLaunchKernelGGL(zero_kernel, dim3((BB * MM) / 1024), dim3(1024), 0, stream, out);
    // main fused kernel: 1024 blocks = 64 b x 16 chunks of 32 tokens
    hipLaunchKernelGGL(qdnn_main, dim3(BB * NCHUNK), dim3(NTHREADS), 0, stream,
                       xx, amp, pha, mix, kr, ki, out);
}

// Round 3
// 174.455 us; speedup vs baseline: 3.1255x; 1.0421x over previous
//
#include <hip/hip_runtime.h>
#include <math.h>

// Problem constants
#define D      50
#define MM     128      // M
#define LL     512      // L
#define BB     64       // B
#define KK     128      // padded concat-K (100 real + 28 zero)
#define KS     136      // LDS V-row stride in shorts: 272 B -> rows advance 4 banks, 2-way (free)
#define LT     64       // tokens per block
#define NCH    8        // L / LT
#define NTHREADS 256

typedef __attribute__((ext_vector_type(8))) short  short8;   // 8 bf16 = 4 VGPR (guide-verified frag type)
typedef __attribute__((ext_vector_type(4))) float  float4v;  // MFMA C/D

// round-to-nearest bf16 split: x ~= hi + lo, |x - hi - lo| <= 2^-18 |x|
__device__ __forceinline__ void bsplit(float x, short& hi, short& lo) {
    unsigned u = __float_as_uint(x);
    unsigned r = u + 0x7FFFu + ((u >> 16) & 1u);
    hi = (short)(r >> 16);
    float res = x - __uint_as_float(r & 0xFFFF0000u);
    unsigned u2 = __float_as_uint(res);
    unsigned r2 = u2 + 0x7FFFu + ((u2 >> 16) & 1u);
    lo = (short)(r2 >> 16);
}

// Prep: blocks 0..7 build per-lane MFMA B-fragments (bf16 hi/lo, real/imag parts)
// for n-tile = blockIdx into ws, plus per-m row norms. Block 8 zeroes out.
// B'[m][k] layouts: Br = [kr | ki | 0], Bi = [-ki | kr | 0] along k (concat at 50).
// Fragment for lane: B'[m = ntile*16 + (lane&15)][k = kstep*32 + (lane>>4)*8 + j].
__global__ void __launch_bounds__(NTHREADS)
qdnn_prep(const float* __restrict__ kernel_real,
          const float* __restrict__ kernel_imag,
          float* __restrict__ out,
          short* __restrict__ ws_frag,   // [128 frag-groups][64 lanes][8 shorts]
          float* __restrict__ ws_norm)   // [128]
{
    const int tid = threadIdx.x;
    if (blockIdx.x == 8) {               // zero-init output (harness poisons 0xAA)
        #pragma unroll
        for (int j = 0; j < (BB * MM) / NTHREADS; ++j)
            out[j * NTHREADS + tid] = 0.0f;
        return;
    }
    const int ntile = blockIdx.x;        // 0..7
    const int lane  = tid & 63;
    const int kstep = tid >> 6;          // 0..3
    const int col   = lane & 15;
    const int g     = lane >> 4;
    const int m     = ntile * 16 + col;
    const float* krow = kernel_real + m * D;
    const float* irow = kernel_imag + m * D;

    short8 fr_hi, fr_lo, fi_hi, fi_lo;
    float np = 0.0f;
    #pragma unroll
    for (int j = 0; j < 8; ++j) {
        const int k = kstep * 32 + g * 8 + j;
        float br = 0.0f, bi = 0.0f;
        if (k < D) {
            const float a = krow[k], c = irow[k];
            br = a; bi = -c;
            np = fmaf(a, a, fmaf(c, c, np));   // ||row||^2 partial (counted once, k<50 only)
        } else if (k < 2 * D) {
            const float a = krow[k - D], c = irow[k - D];
            br = c; bi = a;
        }
        short h, l;
        bsplit(br, h, l); fr_hi[j] = h; fr_lo[j] = l;
        bsplit(bi, h, l); fi_hi[j] = h; fi_lo[j] = l;
    }
    const size_t fb = (size_t)((ntile * 4 + kstep) * 4) * 64 * 8;
    *(short8*)(ws_frag + fb + (size_t)(0 * 64 + lane) * 8) = fr_hi;
    *(short8*)(ws_frag + fb + (size_t)(1 * 64 + lane) * 8) = fr_lo;
    *(short8*)(ws_frag + fb + (size_t)(2 * 64 + lane) * 8) = fi_hi;
    *(short8*)(ws_frag + fb + (size_t)(3 * 64 + lane) * 8) = fi_lo;

    __shared__ float s_nr[NTHREADS];
    s_nr[tid] = np;
    __syncthreads();
    if (tid < 16) {                      // threads with lane&15 == tid cover all k exactly once
        float s = 0.0f;
        #pragma unroll
        for (int u = 0; u < 16; ++u) s += s_nr[tid + 16 * u];
        ws_norm[ntile * 16 + tid] = s;
    }
}

// Main: 512 blocks = 64 b x 8 chunks of 64 tokens. Phases: softmax(w) ->
// gather+sincos+split V into LDS -> barrier -> barrier-free split-bf16 MFMA
// GEMM (Ar, Ai) with fused w-weighted |A|^2 epilogue -> atomic combine.
__global__ void __launch_bounds__(NTHREADS)
qdnn_main(const int*   __restrict__ x,
          const float* __restrict__ amp_table,
          const float* __restrict__ pha_table,
          const float* __restrict__ mix_table,
          const short* __restrict__ ws_frag,
          const float* __restrict__ ws_norm,
          float* __restrict__ out)
{
    __shared__ short s_vhi[LT * KS];     // 17408 B  V = [vr|vi] bf16-hi, K-padded
    __shared__ short s_vlo[LT * KS];     // 17408 B  bf16-lo residual
    __shared__ int   s_x[LL];            //  2048 B
    __shared__ float s_w[LL];            //  2048 B
    __shared__ float s_red[8];           // total ~39 KB

    const int tid    = threadIdx.x;
    const int b      = blockIdx.x >> 3;
    const int lchunk = blockIdx.x & 7;
    const int wave   = tid >> 6;
    const int lane   = tid & 63;

    // ---- phase 0: token ids
    const int* xg = x + b * LL;
    s_x[tid]       = xg[tid];
    s_x[tid + 256] = xg[tid + 256];
    __syncthreads();

    // ---- phase 1: softmax over mix logits (full L, redundant per chunk)
    const float v0 = mix_table[s_x[tid]];
    const float v1 = mix_table[s_x[tid + 256]];
    float lmax = fmaxf(v0, v1);
    #pragma unroll
    for (int off = 32; off > 0; off >>= 1)
        lmax = fmaxf(lmax, __shfl_down(lmax, off));
    if (lane == 0) s_red[wave] = lmax;
    __syncthreads();
    const float bmax = fmaxf(fmaxf(s_red[0], s_red[1]), fmaxf(s_red[2], s_red[3]));
    const float e0 = __expf(v0 - bmax);
    const float e1 = __expf(v1 - bmax);
    s_w[tid]       = e0;
    s_w[tid + 256] = e1;
    float esum = e0 + e1;
    #pragma unroll
    for (int off = 32; off > 0; off >>= 1)
        esum += __shfl_down(esum, off);
    if (lane == 0) s_red[4 + wave] = esum;
    __syncthreads();
    const float inv = 1.0f / (s_red[4] + s_red[5] + s_red[6] + s_red[7]);
    s_w[tid]       *= inv;
    s_w[tid + 256] *= inv;

    // ---- phase 2: build V tile: gather amp/pha, sincos, bf16 hi/lo split
    {
        const int tok   = tid >> 2;          // 0..63
        const int dbase = (tid & 3) * 13;    // 4 threads x 13 d-slots cover 50
        const int gidx  = s_x[lchunk * LT + tok];
        const float* arow = amp_table + (size_t)gidx * D;
        const float* prow = pha_table + (size_t)gidx * D;
        #pragma unroll
        for (int jj = 0; jj < 13; ++jj) {
            const int d = dbase + jj;
            if (d < D) {
                const float a = arow[d], ph = prow[d];
                float sn, cs;
                __sincosf(ph, &sn, &cs);
                short h, l;
                bsplit(a * cs, h, l);
                s_vhi[tok * KS + d] = h;      s_vlo[tok * KS + d] = l;
                bsplit(a * sn, h, l);
                s_vhi[tok * KS + D + d] = h;  s_vlo[tok * KS + D + d] = l;
            }
        }
        // zero K-pad region [100,136)
        for (int j = tid; j < LT * (KS - 2 * D); j += NTHREADS) {
            const int r = j / (KS - 2 * D);
            const int c = 2 * D + (j - r * (KS - 2 * D));
            s_vhi[r * KS + c] = 0;
            s_vlo[r * KS + c] = 0;
        }
    }
    __syncthreads();

    // ---- phase 3: split-bf16 MFMA GEMM + fused epilogue (no further barriers)
    const int l15 = lane & 15;           // A-row within 16-token tile; also output m-col
    const int g   = lane >> 4;
    for (int miter = 0; miter < 2; ++miter) {
        const int ntile = miter * 4 + wave;      // waves cover m-tiles 0..7
        // B-fragments: 16 coalesced dwordx4 loads from L2-resident ws
        short8 fr_hi[4], fr_lo[4], fi_hi[4], fi_lo[4];
        #pragma unroll
        for (int ks = 0; ks < 4; ++ks) {
            const size_t fb = (size_t)((ntile * 4 + ks) * 4) * 64 * 8;
            fr_hi[ks] = *(const short8*)(ws_frag + fb + (size_t)(0 * 64 + lane) * 8);
            fr_lo[ks] = *(const short8*)(ws_frag + fb + (size_t)(1 * 64 + lane) * 8);
            fi_hi[ks] = *(const short8*)(ws_frag + fb + (size_t)(2 * 64 + lane) * 8);
            fi_lo[ks] = *(const short8*)(ws_frag + fb + (size_t)(3 * 64 + lane) * 8);
        }
        const float nrm = ws_norm[ntile * 16 + l15];

        float pm = 0.0f;
        for (int liter = 0; liter < 4; ++liter) {
            const int lb = liter * 16;
            float4v ar[4], ai[4];
            #pragma unroll
            for (int ks = 0; ks < 4; ++ks) {
                ar[ks] = (float4v)(0.0f);
                ai[ks] = (float4v)(0.0f);
            }
            #pragma unroll
            for (int ks = 0; ks < 4; ++ks) {   // 8 independent acc chains of 4
                const int aoff = (lb + l15) * KS + ks * 32 + g * 8;
                const short8 ah = *(const short8*)(s_vhi + aoff);
                const short8 al = *(const short8*)(s_vlo + aoff);
                ar[ks] = __builtin_amdgcn_mfma_f32_16x16x32_bf16(ah, fr_hi[ks], ar[ks], 0, 0, 0);
                ar[ks] = __builtin_amdgcn_mfma_f32_16x16x32_bf16(ah, fr_lo[ks], ar[ks], 0, 0, 0);
                ar[ks] = __builtin_amdgcn_mfma_f32_16x16x32_bf16(al, fr_hi[ks], ar[ks], 0, 0, 0);
                ar[ks] = __builtin_amdgcn_mfma_f32_16x16x32_bf16(al, fr_lo[ks], ar[ks], 0, 0, 0);
                ai[ks] = __builtin_amdgcn_mfma_f32_16x16x32_bf16(ah, fi_hi[ks], ai[ks], 0, 0, 0);
                ai[ks] = __builtin_amdgcn_mfma_f32_16x16x32_bf16(ah, fi_lo[ks], ai[ks], 0, 0, 0);
                ai[ks] = __builtin_amdgcn_mfma_f32_16x16x32_bf16(al, fi_hi[ks], ai[ks], 0, 0, 0);
                ai[ks] = __builtin_amdgcn_mfma_f32_16x16x32_bf16(al, fi_lo[ks], ai[ks], 0, 0, 0);
            }
            // C/D layout: col = lane&15 (m), row = g*4 + reg (l within tile)
            #pragma unroll
            for (int reg = 0; reg < 4; ++reg) {
                const float arr = ar[0][reg] + ar[1][reg] + ar[2][reg] + ar[3][reg];
                const float aii = ai[0][reg] + ai[1][reg] + ai[2][reg] + ai[3][reg];
                const float wl  = s_w[lchunk * LT + lb + g * 4 + reg];
                pm = fmaf(wl, fmaf(arr, arr, aii * aii), pm);
            }
        }
        // reduce over the 4 row-groups (lanes differing in bits 4,5)
        pm += __shfl_xor(pm, 16);
        pm += __shfl_xor(pm, 32);
        if (lane < 16)
            atomicAdd(&out[b * MM + ntile * 16 + l15], pm / nrm);
    }
}

extern "C" void kernel_launch(void* const* d_in, const int* in_sizes, int n_in,
                              void* d_out, int out_size, void* d_ws, size_t ws_size,
                              hipStream_t stream) {
    const int*   xx  = (const int*)d_in[0];
    const float* amp = (const float*)d_in[1];
    const float* pha = (const float*)d_in[2];
    const float* mix = (const float*)d_in[3];
    const float* kr  = (const float*)d_in[4];
    const float* ki  = (const float*)d_in[5];
    float* out = (float*)d_out;

    short* ws_frag = (short*)d_ws;                       // 131072 B
    float* ws_norm = (float*)((char*)d_ws + 131072);     // 512 B

    // prep: B-fragments + norms (blocks 0..7) and output zero-init (block 8)
    hipLaunchKernelGGL(qdnn_prep, dim3(9), dim3(NTHREADS), 0, stream,
                       kr, ki, out, ws_frag, ws_norm);
    // main: 512 blocks = 64 b x 8 token-chunks
    hipLaunchKernelGGL(qdnn_main, dim3(BB * NCH), dim3(NTHREADS), 0, stream,
                       xx, amp, pha, mix, ws_frag, ws_norm, out);
}

// Round 4
// 164.973 us; speedup vs baseline: 3.3051x; 1.0575x over previous
//
#include <hip/hip_runtime.h>
#include <math.h>

// Problem constants
#define D      50
#define MM     128      // M
#define LL     512      // L
#define BB     64       // B
#define KS     136      // LDS V-row stride in shorts (272 B = 16*17, 16B-aligned rows)
#define KSU    68       // uints per V row
#define LT     64       // tokens per block
#define NCH    8        // L / LT
#define NTHREADS 256

typedef __attribute__((ext_vector_type(8))) short  short8;   // 8 bf16 = 4 VGPR
typedef __attribute__((ext_vector_type(4))) float  float4v;  // MFMA C/D

// round-to-nearest bf16 split: x ~= hi + lo, |x - hi - lo| <= ~2^-18 |x|
__device__ __forceinline__ void bsplit(float x, short& hi, short& lo) {
    unsigned u = __float_as_uint(x);
    unsigned r = u + 0x7FFFu + ((u >> 16) & 1u);
    hi = (short)(r >> 16);
    float res = x - __uint_as_float(r & 0xFFFF0000u);
    unsigned u2 = __float_as_uint(res);
    unsigned r2 = u2 + 0x7FFFu + ((u2 >> 16) & 1u);
    lo = (short)(r2 >> 16);
}

// split a pair, pack hi halves and lo halves into uints (little-endian: elem d in low16)
__device__ __forceinline__ void bsplit2(float x0, float x1, unsigned& hiU, unsigned& loU) {
    short h0, l0, h1, l1;
    bsplit(x0, h0, l0);
    bsplit(x1, h1, l1);
    hiU = (unsigned)(unsigned short)h0 | ((unsigned)(unsigned short)h1 << 16);
    loU = (unsigned)(unsigned short)l0 | ((unsigned)(unsigned short)l1 << 16);
}

// Prep, 73 blocks:
//  blocks 0..7 : per-lane MFMA B-fragments (bf16 hi/lo, real/imag) + 1/||row||^2
//  block  8    : zero-init out (harness poisons 0xAA)
//  blocks 9..72: per-b softmax over mix logits -> ws_w[b][l]  (dedup: was 8x per chunk)
__global__ void __launch_bounds__(NTHREADS)
qdnn_prep(const int*   __restrict__ x,
          const float* __restrict__ mix_table,
          const float* __restrict__ kernel_real,
          const float* __restrict__ kernel_imag,
          float* __restrict__ out,
          short* __restrict__ ws_frag,    // [32 (ntile,ks)][4 kinds][64 lanes][8 shorts]
          float* __restrict__ ws_inorm,   // [128] 1/||row||^2
          float* __restrict__ ws_w)       // [64][512]
{
    __shared__ float s_nr[NTHREADS];
    __shared__ float s_red[8];
    const int tid = threadIdx.x;
    const int blk = blockIdx.x;

    if (blk < 8) {
        // ---- B-fragment build. B'[m][k]: Br = [kr|ki|0], Bi = [-ki|kr|0] along k.
        // lane frag: B'[m = ntile*16 + (lane&15)][k = kstep*32 + (lane>>4)*8 + j]
        const int ntile = blk;
        const int lane  = tid & 63;
        const int kstep = tid >> 6;
        const int col   = lane & 15;
        const int g     = lane >> 4;
        const int m     = ntile * 16 + col;
        const float* krow = kernel_real + m * D;
        const float* irow = kernel_imag + m * D;

        short8 fr_hi, fr_lo, fi_hi, fi_lo;
        float np = 0.0f;
        #pragma unroll
        for (int j = 0; j < 8; ++j) {
            const int k = kstep * 32 + g * 8 + j;
            float br = 0.0f, bi = 0.0f;
            if (k < D) {
                const float a = krow[k], c = irow[k];
                br = a; bi = -c;
                np = fmaf(a, a, fmaf(c, c, np));   // counted once (k<50 only)
            } else if (k < 2 * D) {
                const float a = krow[k - D], c = irow[k - D];
                br = c; bi = a;
            }
            short h, l;
            bsplit(br, h, l); fr_hi[j] = h; fr_lo[j] = l;
            bsplit(bi, h, l); fi_hi[j] = h; fi_lo[j] = l;
        }
        const size_t fb = (size_t)((ntile * 4 + kstep) * 4) * 64 * 8;
        *(short8*)(ws_frag + fb + (size_t)(0 * 64 + lane) * 8) = fr_hi;
        *(short8*)(ws_frag + fb + (size_t)(1 * 64 + lane) * 8) = fr_lo;
        *(short8*)(ws_frag + fb + (size_t)(2 * 64 + lane) * 8) = fi_hi;
        *(short8*)(ws_frag + fb + (size_t)(3 * 64 + lane) * 8) = fi_lo;

        s_nr[tid] = np;
        __syncthreads();
        if (tid < 16) {                  // threads with lane&15==tid cover all k once
            float s = 0.0f;
            #pragma unroll
            for (int u = 0; u < 16; ++u) s += s_nr[tid + 16 * u];
            ws_inorm[ntile * 16 + tid] = 1.0f / s;
        }
    } else if (blk == 8) {
        // ---- zero-init output
        #pragma unroll
        for (int j = 0; j < (BB * MM) / NTHREADS; ++j)
            out[j * NTHREADS + tid] = 0.0f;
    } else {
        // ---- softmax for sequence b
        const int b = blk - 9;
        const int wave = tid >> 6, lane = tid & 63;
        const int g0 = x[b * LL + tid];
        const int g1 = x[b * LL + tid + 256];
        const float v0 = mix_table[g0];
        const float v1 = mix_table[g1];
        float lmax = fmaxf(v0, v1);
        #pragma unroll
        for (int off = 32; off > 0; off >>= 1)
            lmax = fmaxf(lmax, __shfl_down(lmax, off));
        if (lane == 0) s_red[wave] = lmax;
        __syncthreads();
        const float bmax = fmaxf(fmaxf(s_red[0], s_red[1]), fmaxf(s_red[2], s_red[3]));
        const float e0 = __expf(v0 - bmax);
        const float e1 = __expf(v1 - bmax);
        float esum = e0 + e1;
        #pragma unroll
        for (int off = 32; off > 0; off >>= 1)
            esum += __shfl_down(esum, off);
        if (lane == 0) s_red[4 + wave] = esum;
        __syncthreads();
        const float inv = 1.0f / (s_red[4] + s_red[5] + s_red[6] + s_red[7]);
        ws_w[b * LL + tid]       = e0 * inv;
        ws_w[b * LL + tid + 256] = e1 * inv;
    }
}

// Main: 512 blocks = 64 b x 8 chunks of 64 tokens. One barrier total:
// [gather V (float2) + sincos + bf16 split -> LDS] -> barrier ->
// [split-bf16 MFMA (hh+hl+lh; ll dropped, ~2^-18 rel) + fused w-|A|^2 epilogue].
__global__ void __launch_bounds__(NTHREADS)
qdnn_main(const int*   __restrict__ x,
          const float* __restrict__ amp_table,
          const float* __restrict__ pha_table,
          const short* __restrict__ ws_frag,
          const float* __restrict__ ws_inorm,
          const float* __restrict__ ws_w,
          float* __restrict__ out)
{
    __shared__ short s_vhi[LT * KS];     // 17408 B  V = [vr|vi] bf16-hi
    __shared__ short s_vlo[LT * KS];     // 17408 B  bf16-lo residual
    __shared__ float s_w64[LT];          // total ~35 KB

    const int tid    = threadIdx.x;
    const int b      = blockIdx.x >> 3;
    const int lchunk = blockIdx.x & 7;
    const int wave   = tid >> 6;
    const int lane   = tid & 63;

    // ---- phase A: build V tile (4 threads per token, float2 pair lanes e=t4+4j)
    {
        const int tok = tid >> 2;
        const int t4  = tid & 3;
        const int gidx = x[b * LL + lchunk * LT + tok];   // 4 threads broadcast-load
        const float* arow = amp_table + (size_t)gidx * D; // row base byte = gidx*200, 8B-aligned
        const float* prow = pha_table + (size_t)gidx * D;
        unsigned* vhiU = (unsigned*)s_vhi;
        unsigned* vloU = (unsigned*)s_vlo;
        const int rb = tok * KSU;
        #pragma unroll
        for (int j = 0; j < 7; ++j) {
            const int e = t4 + 4 * j;                     // pair index, d = 2e
            if (e < 25) {
                const float2 a2 = *(const float2*)(arow + 2 * e);
                const float2 p2 = *(const float2*)(prow + 2 * e);
                float sn0, cs0, sn1, cs1;
                __sincosf(p2.x, &sn0, &cs0);
                __sincosf(p2.y, &sn1, &cs1);
                unsigned hu, lu;
                bsplit2(a2.x * cs0, a2.y * cs1, hu, lu);  // vr pair -> d, d+1
                vhiU[rb + e] = hu;  vloU[rb + e] = lu;
                bsplit2(a2.x * sn0, a2.y * sn1, hu, lu);  // vi pair -> D+d (50+2e, even)
                vhiU[rb + 25 + e] = hu;  vloU[rb + 25 + e] = lu;
            }
        }
        // zero K-pad uints [50,68) per row
        for (int j = tid; j < LT * (KSU - 50); j += NTHREADS) {
            const int r = j / (KSU - 50);
            const int c = j - r * (KSU - 50);
            vhiU[r * KSU + 50 + c] = 0;
            vloU[r * KSU + 50 + c] = 0;
        }
        if (tid < LT) s_w64[tid] = ws_w[b * LL + lchunk * LT + tid];
    }
    __syncthreads();

    // ---- phase B: MFMA GEMM + fused epilogue (barrier-free)
    const int l15 = lane & 15;           // A-row within 16-token tile; also output m-col
    const int g   = lane >> 4;
    #pragma unroll
    for (int miter = 0; miter < 2; ++miter) {
        const int ntile = miter * 4 + wave;      // waves cover m-tiles 0..7
        short8 fr_hi[4], fr_lo[4], fi_hi[4], fi_lo[4];
        #pragma unroll
        for (int ks = 0; ks < 4; ++ks) {
            const size_t fb = (size_t)((ntile * 4 + ks) * 4) * 64 * 8;
            fr_hi[ks] = *(const short8*)(ws_frag + fb + (size_t)(0 * 64 + lane) * 8);
            fr_lo[ks] = *(const short8*)(ws_frag + fb + (size_t)(1 * 64 + lane) * 8);
            fi_hi[ks] = *(const short8*)(ws_frag + fb + (size_t)(2 * 64 + lane) * 8);
            fi_lo[ks] = *(const short8*)(ws_frag + fb + (size_t)(3 * 64 + lane) * 8);
        }
        const float inrm = ws_inorm[ntile * 16 + l15];

        float pm = 0.0f;
        #pragma unroll
        for (int liter = 0; liter < 4; ++liter) {
            const int lb = liter * 16;
            float4v ar[4], ai[4];
            #pragma unroll
            for (int ks = 0; ks < 4; ++ks) {
                ar[ks] = (float4v)(0.0f);
                ai[ks] = (float4v)(0.0f);
            }
            #pragma unroll
            for (int ks = 0; ks < 4; ++ks) {     // 8 independent acc chains of 3
                const int aoff = (lb + l15) * KS + ks * 32 + g * 8;
                const short8 ah = *(const short8*)(s_vhi + aoff);
                const short8 al = *(const short8*)(s_vlo + aoff);
                ar[ks] = __builtin_amdgcn_mfma_f32_16x16x32_bf16(ah, fr_hi[ks], ar[ks], 0, 0, 0);
                ar[ks] = __builtin_amdgcn_mfma_f32_16x16x32_bf16(ah, fr_lo[ks], ar[ks], 0, 0, 0);
                ar[ks] = __builtin_amdgcn_mfma_f32_16x16x32_bf16(al, fr_hi[ks], ar[ks], 0, 0, 0);
                ai[ks] = __builtin_amdgcn_mfma_f32_16x16x32_bf16(ah, fi_hi[ks], ai[ks], 0, 0, 0);
                ai[ks] = __builtin_amdgcn_mfma_f32_16x16x32_bf16(ah, fi_lo[ks], ai[ks], 0, 0, 0);
                ai[ks] = __builtin_amdgcn_mfma_f32_16x16x32_bf16(al, fi_hi[ks], ai[ks], 0, 0, 0);
            }
            // C/D layout: col = lane&15 (m), row = g*4 + reg (token within tile)
            #pragma unroll
            for (int reg = 0; reg < 4; ++reg) {
                const float arr = ar[0][reg] + ar[1][reg] + ar[2][reg] + ar[3][reg];
                const float aii = ai[0][reg] + ai[1][reg] + ai[2][reg] + ai[3][reg];
                const float wl  = s_w64[lb + g * 4 + reg];
                pm = fmaf(wl, fmaf(arr, arr, aii * aii), pm);
            }
        }
        pm += __shfl_xor(pm, 16);
        pm += __shfl_xor(pm, 32);
        if (lane < 16)
            atomicAdd(&out[b * MM + ntile * 16 + l15], pm * inrm);
    }
}

extern "C" void kernel_launch(void* const* d_in, const int* in_sizes, int n_in,
                              void* d_out, int out_size, void* d_ws, size_t ws_size,
                              hipStream_t stream) {
    const int*   xx  = (const int*)d_in[0];
    const float* amp = (const float*)d_in[1];
    const float* pha = (const float*)d_in[2];
    const float* mix = (const float*)d_in[3];
    const float* kr  = (const float*)d_in[4];
    const float* ki  = (const float*)d_in[5];
    float* out = (float*)d_out;

    short* ws_frag  = (short*)d_ws;                        // 131072 B
    float* ws_inorm = (float*)((char*)d_ws + 131072);      //    512 B
    float* ws_w     = (float*)((char*)d_ws + 131584);      // 131072 B

    // prep: fragments (0..7) + out zero (8) + per-b softmax (9..72)
    hipLaunchKernelGGL(qdnn_prep, dim3(9 + BB), dim3(NTHREADS), 0, stream,
                       xx, mix, kr, ki, out, ws_frag, ws_inorm, ws_w);
    // main: 512 blocks = 64 b x 8 token-chunks
    hipLaunchKernelGGL(qdnn_main, dim3(BB * NCH), dim3(NTHREADS), 0, stream,
                       xx, amp, pha, ws_frag, ws_inorm, ws_w, out);
}